// Round 14
// baseline (280.396 us; speedup 1.0000x reference)
//
#include <hip/hip_runtime.h>
#include <hip/hip_bf16.h>

#define NUM_HEADS   32
#define NUM_KV_HEADS 8
#define HEAD_DIM    128
#define GQA          4
#define Q_LEN      256
#define MAX_PAGES  128
#define PAGE_SIZE   16
#define SCALE 0.08838834764831845f
#define LOG2E 1.44269504088896340736f
#define RESCALE_THR 8.0f

// 64-token chunks
#define NCH_MAX   36
#define CHUNK_B   16384
#define KSTREAM   ((size_t)NCH_MAX * CHUNK_B)
#define NITEMS    512

typedef __bf16 bf16x8 __attribute__((ext_vector_type(8)));
typedef float  f32x4  __attribute__((ext_vector_type(4)));

union B8 { uint4 u; bf16x8 v; };

__device__ __forceinline__ unsigned f2bf(float x){
    unsigned u = __builtin_bit_cast(unsigned, x);
    return (u + 0x7fffu + ((u >> 16) & 1u)) >> 16;
}
__device__ __forceinline__ unsigned pack2(float lo, float hi){
    return f2bf(lo) | (f2bf(hi) << 16);
}

typedef __attribute__((address_space(3))) unsigned char lds_as3_t;
typedef const __attribute__((address_space(1))) void gas_v;
typedef __attribute__((address_space(3))) void las_v;

#define GLD16(g, l) __builtin_amdgcn_global_load_lds((gas_v*)(g), (las_v*)(l), 16, 0, 0)

#define TRR(dst, base, OFF) asm volatile("ds_read_b64_tr_b16 %0, %1 offset:" OFF \
                                         : "=v"(dst) : "v"(base))

// ============================ pre-pass: gather + bf16 (K row-major, V tr-subtiled) ============================
__global__ __launch_bounds__(256) void prep_kernel(
    const float* __restrict__ knew,
    const float* __restrict__ vnew,
    const float* __restrict__ kcache,
    const float* __restrict__ vcache,
    const int*   __restrict__ ptab,
    const int*   __restrict__ ctxlens,
    unsigned char* __restrict__ kimg,
    unsigned char* __restrict__ vimg)
{
    const int ch  = blockIdx.x;
    const int kvh = blockIdx.y;
    const int b   = blockIdx.z;
    const int ctxlen = ctxlens[b];
    const int lim = ctxlen + Q_LEN;
    const int base = ch * 64;
    if (base >= lim) return;

    const int tid  = threadIdx.x;
    const int srow = tid >> 2;
    const int seg  = tid & 3;
    const int t    = base + srow;

    unsigned char* kdst = kimg + (size_t)(b * 8 + kvh) * KSTREAM + (size_t)ch * CHUNK_B;
    unsigned char* vdst = vimg + (size_t)(b * 8 + kvh) * KSTREAM + (size_t)ch * CHUNK_B;
    const int vbyte0 = (srow >> 2) * 128 + (srow & 3) * 32;

    if (t < lim){
        size_t roff;
        const float *ksrc, *vsrc;
        if (t < ctxlen){
            const int page = ptab[b * MAX_PAGES + (t >> 4)];
            roff = ((size_t)(page * PAGE_SIZE + (t & 15)) * NUM_KV_HEADS + kvh) * HEAD_DIM;
            ksrc = kcache + roff; vsrc = vcache + roff;
        } else {
            roff = ((size_t)(b * Q_LEN + (t - ctxlen)) * NUM_KV_HEADS + kvh) * HEAD_DIM;
            ksrc = knew + roff; vsrc = vnew + roff;
        }
        const float* kr = ksrc + seg * 32;
        const float* vr = vsrc + seg * 32;
        #pragma unroll
        for (int i = 0; i < 4; ++i){
            float4 a  = *(const float4*)(kr + i * 8);
            float4 c4 = *(const float4*)(kr + i * 8 + 4);
            uint4 wv;
            wv.x = pack2(a.x, a.y);  wv.y = pack2(a.z, a.w);
            wv.z = pack2(c4.x, c4.y); wv.w = pack2(c4.z, c4.w);
            *(uint4*)(kdst + srow * 256 + seg * 64 + i * 16) = wv;   // plain row-major
        }
        #pragma unroll
        for (int db = 0; db < 2; ++db){
            const float4 a0 = *(const float4*)(vr + db * 16 + 0);
            const float4 a1 = *(const float4*)(vr + db * 16 + 4);
            const float4 a2 = *(const float4*)(vr + db * 16 + 8);
            const float4 a3 = *(const float4*)(vr + db * 16 + 12);
            uint4 w0, w1;
            w0.x = pack2(a0.x, a0.y); w0.y = pack2(a0.z, a0.w);
            w0.z = pack2(a1.x, a1.y); w0.w = pack2(a1.z, a1.w);
            w1.x = pack2(a2.x, a2.y); w1.y = pack2(a2.z, a2.w);
            w1.z = pack2(a3.x, a3.y); w1.w = pack2(a3.z, a3.w);
            const int dbk = seg * 2 + db;
            *(uint4*)(vdst + dbk * 2048 + vbyte0)      = w0;
            *(uint4*)(vdst + dbk * 2048 + vbyte0 + 16) = w1;
        }
    } else {
        const uint4 z = {0u, 0u, 0u, 0u};
        #pragma unroll
        for (int i = 0; i < 4; ++i)
            *(uint4*)(kdst + srow * 256 + seg * 64 + i * 16) = z;
        #pragma unroll
        for (int db = 0; db < 2; ++db){
            const int dbk = seg * 2 + db;
            *(uint4*)(vdst + dbk * 2048 + vbyte0)      = z;
            *(uint4*)(vdst + dbk * 2048 + vbyte0 + 16) = z;
        }
    }
}

// ============================ attention kernel (K direct global->VGPR, V via LDS tr-read) ============================
// LDS 32KB: V dbuf [2][16KB]. 2 blocks/CU.
// Per-chunk: lgkm(0) -> s_barrier -> STAGE_V(ch+1) -> vmcnt(4) [V(ch)+K(ch) landed] ->
//            QK (32 MFMA, K in regs) -> issue 32 tr_reads -> KLOAD(ch+1) -> softmax (VALU) ->
//            lgkm(0) -> 32 PV MFMAs.
__global__ __launch_bounds__(256, 2) void attn_kernel(
    const float* __restrict__ q,
    const int*   __restrict__ ctxlens,
    float*       __restrict__ out,
    const unsigned char* __restrict__ kimg,
    const unsigned char* __restrict__ vimg)
{
    __shared__ __align__(16) unsigned char lds[32768];

    const int tid  = threadIdx.x;
    const int w    = tid >> 6;
    const int lane = tid & 63;
    const int hh   = lane >> 4;
    const int cq   = lane & 15;

    const unsigned ldsb3 = (unsigned)(unsigned long long)(lds_as3_t*)(&lds[0]);

    const int item0 = blockIdx.x;                 // 0..511, long items first
    const int b   = item0 & 7;
    const int kvh = (item0 >> 3) & 7;
    const int s32 = 7 - (item0 >> 6);

    const int s0 = s32 * 32;
    const int ctxlen = ctxlens[b];
    const int vlim = ctxlen + (s32 + 1) * 32;
    const int nch  = (vlim + 63) >> 6;
    const int hq = kvh * GQA + w;

    const unsigned char* kstream = kimg + (size_t)(b * 8 + kvh) * KSTREAM;
    const unsigned char* vstream = vimg + (size_t)(b * 8 + kvh) * KSTREAM;
    const unsigned char* klane   = kstream + (cq * 256 + hh * 16);   // per-lane K frag base

    #define STAGE_V(CH, PB) do { \
        const unsigned char* vg_ = vstream + (size_t)(CH) * CHUNK_B + (w * 4096 + lane * 16); \
        _Pragma("unroll") \
        for (int i_ = 0; i_ < 4; ++i_){ \
            GLD16(vg_ + i_ * 1024, lds + (PB) * 16384 + w * 4096 + i_ * 1024); \
        } \
    } while (0)

    B8 kf[4][4];   // [tf][c] K fragments for current chunk (64 VGPR, persistent)
    #define KLOAD(CH) do { \
        const unsigned char* kc_ = klane + (size_t)(CH) * CHUNK_B; \
        _Pragma("unroll") \
        for (int tf_ = 0; tf_ < 4; ++tf_){ \
            _Pragma("unroll") \
            for (int c_ = 0; c_ < 4; ++c_){ \
                kf[tf_][c_].u = *(const uint4*)(kc_ + tf_ * 4096 + c_ * 64); \
            } \
        } \
    } while (0)

    KLOAD(0);          // 16 global_load_dwordx4 -> VGPR
    STAGE_V(0, 0);     // 4 GLD16 -> LDS

    // Q fragments (B-operand), two 16-row tiles, pre-scaled into log2 domain
    B8 qf[2][4];
    #pragma unroll
    for (int u = 0; u < 2; ++u){
        const float* qrow = q + (size_t)(b * Q_LEN + s0 + u * 16 + cq) * (NUM_HEADS * HEAD_DIM)
                              + hq * HEAD_DIM;
        #pragma unroll
        for (int c = 0; c < 4; ++c){
            const float4 f0 = *(const float4*)(qrow + c * 32 + 8 * hh);
            const float4 f1 = *(const float4*)(qrow + c * 32 + 8 * hh + 4);
            const float sc = SCALE * LOG2E;
            qf[u][c].u.x = pack2(f0.x * sc, f0.y * sc);
            qf[u][c].u.y = pack2(f0.z * sc, f0.w * sc);
            qf[u][c].u.z = pack2(f1.x * sc, f1.y * sc);
            qf[u][c].u.w = pack2(f1.z * sc, f1.w * sc);
        }
    }

    f32x4 acc[2][8] = {};
    float mrun[2] = {-1e30f, -1e30f};
    float lp[2]   = {0.f, 0.f};

    for (int ch = 0; ch < nch; ++ch){
        const int pb = ch & 1;

        // ---- pipeline head: WAR barrier, V prefetch issue, counted RAW wait ----
        asm volatile("s_waitcnt lgkmcnt(0)" ::: "memory");
        __builtin_amdgcn_s_barrier();
        __builtin_amdgcn_sched_barrier(0);
        if (ch + 1 < nch) {
            STAGE_V(ch + 1, pb ^ 1);
            __builtin_amdgcn_sched_barrier(0);
            asm volatile("s_waitcnt vmcnt(4)" ::: "memory");   // V(ch) in LDS, K(ch) in regs
        } else {
            asm volatile("s_waitcnt vmcnt(0)" ::: "memory");
        }
        __builtin_amdgcn_sched_barrier(0);

        const int base = ch * 64;

        // ---------------- QK^T (swapped, K in registers): st[u][tf] = S^T[t][q] ----------------
        __builtin_amdgcn_s_setprio(1);
        f32x4 st[2][4] = {};
        #pragma unroll
        for (int c = 0; c < 4; ++c){
            #pragma unroll
            for (int tf = 0; tf < 4; ++tf){
                st[0][tf] = __builtin_amdgcn_mfma_f32_16x16x32_bf16(kf[tf][c].v, qf[0][c].v, st[0][tf], 0, 0, 0);
                st[1][tf] = __builtin_amdgcn_mfma_f32_16x16x32_bf16(kf[tf][c].v, qf[1][c].v, st[1][tf], 0, 0, 0);
            }
        }
        __builtin_amdgcn_s_setprio(0);

        // ---------------- EARLY ISSUE: all 32 V tr_reads (latency drains under softmax) ----------------
        const unsigned trb = ldsb3 + (unsigned)(pb * 16384) + (unsigned)(hh * 128 + cq * 8);
        unsigned long long v00,v01,v02,v03,v04,v05,v06,v07,v08,v09,v10,v11,v12,v13,v14,v15;
        unsigned long long v16,v17,v18,v19,v20,v21,v22,v23,v24,v25,v26,v27,v28,v29,v30,v31;
        __builtin_amdgcn_sched_barrier(0);
        // kk=0, dc=0..7 (offsets dc*2048 + half*512)
        TRR(v00, trb, "0");     TRR(v01, trb, "512");
        TRR(v02, trb, "2048");  TRR(v03, trb, "2560");
        TRR(v04, trb, "4096");  TRR(v05, trb, "4608");
        TRR(v06, trb, "6144");  TRR(v07, trb, "6656");
        TRR(v08, trb, "8192");  TRR(v09, trb, "8704");
        TRR(v10, trb, "10240"); TRR(v11, trb, "10752");
        TRR(v12, trb, "12288"); TRR(v13, trb, "12800");
        TRR(v14, trb, "14336"); TRR(v15, trb, "14848");
        // kk=1, dc=0..7 (offsets dc*2048 + 1024 + half*512)
        TRR(v16, trb, "1024");  TRR(v17, trb, "1536");
        TRR(v18, trb, "3072");  TRR(v19, trb, "3584");
        TRR(v20, trb, "5120");  TRR(v21, trb, "5632");
        TRR(v22, trb, "7168");  TRR(v23, trb, "7680");
        TRR(v24, trb, "9216");  TRR(v25, trb, "9728");
        TRR(v26, trb, "11264"); TRR(v27, trb, "11776");
        TRR(v28, trb, "13312"); TRR(v29, trb, "13824");
        TRR(v30, trb, "15360"); TRR(v31, trb, "15872");
        __builtin_amdgcn_sched_barrier(0);

        // ---- K prefetch for next chunk (regs free after QK; lands during next-chunk wait) ----
        if (ch + 1 < nch) KLOAD(ch + 1);

        // ---------------- softmax (shuffle-free defer-max; lgkm-free steady state) ----------------
        B8 af[2][2];
        const bool interior = (base + 64 <= vlim);
        #pragma unroll
        for (int u = 0; u < 2; ++u){
            float p[4][4];
            float pml = -1e30f;
            if (interior){
                #pragma unroll
                for (int tf = 0; tf < 4; ++tf){
                    #pragma unroll
                    for (int r = 0; r < 4; ++r){
                        const float s = st[u][tf][r];
                        p[tf][r] = s;
                        pml = fmaxf(pml, s);
                    }
                }
            } else {
                #pragma unroll
                for (int tf = 0; tf < 4; ++tf){
                    #pragma unroll
                    for (int r = 0; r < 4; ++r){
                        const int t = base + tf * 16 + hh * 4 + r;
                        const float s = (t < vlim) ? st[u][tf][r] : -1e30f;
                        p[tf][r] = s;
                        pml = fmaxf(pml, s);
                    }
                }
            }
            if (!__all(pml <= mrun[u] + RESCALE_THR)){
                float pm = fmaxf(pml, __shfl_xor(pml, 16));
                pm = fmaxf(pm, __shfl_xor(pm, 32));
                const float mnew  = fmaxf(mrun[u], pm);
                const float alpha = __builtin_amdgcn_exp2f(mrun[u] - mnew);
                mrun[u] = mnew;
                lp[u] *= alpha;
                float a4[4];
                #pragma unroll
                for (int r = 0; r < 4; ++r) a4[r] = __shfl(alpha, hh * 20 + r);
                #pragma unroll
                for (int dc = 0; dc < 8; ++dc){
                    #pragma unroll
                    for (int r = 0; r < 4; ++r) acc[u][dc][r] *= a4[r];
                }
            }
            const float m = mrun[u];
            float rsum = 0.f;
            #pragma unroll
            for (int tf = 0; tf < 4; ++tf){
                #pragma unroll
                for (int r = 0; r < 4; ++r){
                    const float e = __builtin_amdgcn_exp2f(p[tf][r] - m);
                    p[tf][r] = e;
                    rsum += e;
                }
            }
            lp[u] += rsum;

            // k-axis mapping: t(kk, 8hh+j) = 32kk + 16*(j>>2) + 4hh + (j&3)
            unsigned pk01[4], pk23[4];
            #pragma unroll
            for (int tf = 0; tf < 4; ++tf){
                pk01[tf] = pack2(p[tf][0], p[tf][1]);
                pk23[tf] = pack2(p[tf][2], p[tf][3]);
            }
            af[u][0].u.x = pk01[0]; af[u][0].u.y = pk23[0]; af[u][0].u.z = pk01[1]; af[u][0].u.w = pk23[1];
            af[u][1].u.x = pk01[2]; af[u][1].u.y = pk23[2]; af[u][1].u.z = pk01[3]; af[u][1].u.w = pk23[3];
        }

        // ---------------- PV: single wait, 32 MFMAs back-to-back ----------------
        {
            asm volatile("s_waitcnt lgkmcnt(0)" ::: "memory");
            __builtin_amdgcn_sched_barrier(0);
            __builtin_amdgcn_s_setprio(1);
            B8 vf;
            #define PVM(VA, VB, KK, DC) \
                vf.u.x=(unsigned)(VA); vf.u.y=(unsigned)((VA)>>32); \
                vf.u.z=(unsigned)(VB); vf.u.w=(unsigned)((VB)>>32); \
                acc[0][DC] = __builtin_amdgcn_mfma_f32_16x16x32_bf16(af[0][KK].v, vf.v, acc[0][DC], 0, 0, 0); \
                acc[1][DC] = __builtin_amdgcn_mfma_f32_16x16x32_bf16(af[1][KK].v, vf.v, acc[1][DC], 0, 0, 0);
            PVM(v00, v01, 0, 0)  PVM(v02, v03, 0, 1)  PVM(v04, v05, 0, 2)  PVM(v06, v07, 0, 3)
            PVM(v08, v09, 0, 4)  PVM(v10, v11, 0, 5)  PVM(v12, v13, 0, 6)  PVM(v14, v15, 0, 7)
            PVM(v16, v17, 1, 0)  PVM(v18, v19, 1, 1)  PVM(v20, v21, 1, 2)  PVM(v22, v23, 1, 3)
            PVM(v24, v25, 1, 4)  PVM(v26, v27, 1, 5)  PVM(v28, v29, 1, 6)  PVM(v30, v31, 1, 7)
            #undef PVM
            __builtin_amdgcn_s_setprio(0);
        }
        // no end-of-chunk barrier: next iteration's top barrier provides WAR separation
    }

    // ---------------- epilogue: normalize + direct write ----------------
    #pragma unroll
    for (int u = 0; u < 2; ++u){
        float l = lp[u];
        l += __shfl_xor(l, 16);
        l += __shfl_xor(l, 32);
        const float li = 1.0f / l;
        float li4[4];
        #pragma unroll
        for (int r = 0; r < 4; ++r) li4[r] = __shfl(li, hh * 20 + r);
        #pragma unroll
        for (int dc = 0; dc < 8; ++dc){
            #pragma unroll
            for (int r = 0; r < 4; ++r){
                const int so = s0 + u * 16 + hh * 4 + r;
                out[(size_t)(b * Q_LEN + so) * (NUM_HEADS * HEAD_DIM) + hq * HEAD_DIM + dc * 16 + cq]
                    = acc[u][dc][r] * li4[r];
            }
        }
    }
    #undef STAGE_V
    #undef KLOAD
}

extern "C" void kernel_launch(void* const* d_in, const int* in_sizes, int n_in,
                              void* d_out, int out_size, void* d_ws, size_t ws_size,
                              hipStream_t stream) {
    const float* q  = (const float*)d_in[0];
    const float* k  = (const float*)d_in[1];
    const float* v  = (const float*)d_in[2];
    const float* kc = (const float*)d_in[3];
    const float* vc = (const float*)d_in[4];
    const int*   pt = (const int*)d_in[5];
    const int*   cl = (const int*)d_in[6];
    float* o = (float*)d_out;

    unsigned char* kimg = (unsigned char*)d_ws + 256;
    unsigned char* vimg = kimg + (size_t)64 * KSTREAM;

    prep_kernel<<<dim3(NCH_MAX, 8, 8), 256, 0, stream>>>(k, v, kc, vc, pt, cl, kimg, vimg);
    attn_kernel<<<NITEMS, 256, 0, stream>>>(q, cl, o, kimg, vimg);
}

// Round 15
// 113.226 us; speedup vs baseline: 2.4764x; 2.4764x over previous
//
#include <hip/hip_runtime.h>
#include <hip/hip_bf16.h>

#define NUM_HEADS   32
#define NUM_KV_HEADS 8
#define HEAD_DIM    128
#define GQA          4
#define Q_LEN      256
#define MAX_PAGES  128
#define PAGE_SIZE   16
#define SCALE 0.08838834764831845f
#define LOG2E 1.44269504088896340736f
#define RESCALE_THR 8.0f

// 64-token chunks (best measured per-chunk economics)
#define NCH_MAX   36
#define CHUNK_B   16384
#define KSTREAM   ((size_t)NCH_MAX * CHUNK_B)
#define NITEMS    512

typedef __bf16 bf16x8 __attribute__((ext_vector_type(8)));
typedef float  f32x4  __attribute__((ext_vector_type(4)));

union B8 { uint4 u; bf16x8 v; };

__device__ __forceinline__ unsigned f2bf(float x){
    unsigned u = __builtin_bit_cast(unsigned, x);
    return (u + 0x7fffu + ((u >> 16) & 1u)) >> 16;
}
__device__ __forceinline__ unsigned pack2(float lo, float hi){
    return f2bf(lo) | (f2bf(hi) << 16);
}

typedef __attribute__((address_space(3))) unsigned char lds_as3_t;
typedef const __attribute__((address_space(1))) void gas_v;
typedef __attribute__((address_space(3))) void las_v;

#define GLD16(g, l) __builtin_amdgcn_global_load_lds((gas_v*)(g), (las_v*)(l), 16, 0, 0)

#define TRR(dst, base, OFF) asm volatile("ds_read_b64_tr_b16 %0, %1 offset:" OFF \
                                         : "=v"(dst) : "v"(base))

// ============================ pre-pass: gather + bf16 + pre-swizzle (64-t chunks) ============================
__global__ __launch_bounds__(256) void prep_kernel(
    const float* __restrict__ knew,
    const float* __restrict__ vnew,
    const float* __restrict__ kcache,
    const float* __restrict__ vcache,
    const int*   __restrict__ ptab,
    const int*   __restrict__ ctxlens,
    unsigned char* __restrict__ kimg,
    unsigned char* __restrict__ vimg)
{
    const int ch  = blockIdx.x;
    const int kvh = blockIdx.y;
    const int b   = blockIdx.z;
    const int ctxlen = ctxlens[b];
    const int lim = ctxlen + Q_LEN;
    const int base = ch * 64;
    if (base >= lim) return;

    const int tid  = threadIdx.x;
    const int srow = tid >> 2;
    const int seg  = tid & 3;
    const int t    = base + srow;

    unsigned char* kdst = kimg + (size_t)(b * 8 + kvh) * KSTREAM + (size_t)ch * CHUNK_B;
    unsigned char* vdst = vimg + (size_t)(b * 8 + kvh) * KSTREAM + (size_t)ch * CHUNK_B;
    const int swz    = (srow & 7) << 4;
    const int vbyte0 = (srow >> 2) * 128 + (srow & 3) * 32;

    if (t < lim){
        size_t roff;
        const float *ksrc, *vsrc;
        if (t < ctxlen){
            const int page = ptab[b * MAX_PAGES + (t >> 4)];
            roff = ((size_t)(page * PAGE_SIZE + (t & 15)) * NUM_KV_HEADS + kvh) * HEAD_DIM;
            ksrc = kcache + roff; vsrc = vcache + roff;
        } else {
            roff = ((size_t)(b * Q_LEN + (t - ctxlen)) * NUM_KV_HEADS + kvh) * HEAD_DIM;
            ksrc = knew + roff; vsrc = vnew + roff;
        }
        const float* kr = ksrc + seg * 32;
        const float* vr = vsrc + seg * 32;
        #pragma unroll
        for (int i = 0; i < 4; ++i){
            float4 a  = *(const float4*)(kr + i * 8);
            float4 c4 = *(const float4*)(kr + i * 8 + 4);
            uint4 wv;
            wv.x = pack2(a.x, a.y);  wv.y = pack2(a.z, a.w);
            wv.z = pack2(c4.x, c4.y); wv.w = pack2(c4.z, c4.w);
            *(uint4*)(kdst + srow * 256 + ((seg * 64 + i * 16) ^ swz)) = wv;
        }
        #pragma unroll
        for (int db = 0; db < 2; ++db){
            const float4 a0 = *(const float4*)(vr + db * 16 + 0);
            const float4 a1 = *(const float4*)(vr + db * 16 + 4);
            const float4 a2 = *(const float4*)(vr + db * 16 + 8);
            const float4 a3 = *(const float4*)(vr + db * 16 + 12);
            uint4 w0, w1;
            w0.x = pack2(a0.x, a0.y); w0.y = pack2(a0.z, a0.w);
            w0.z = pack2(a1.x, a1.y); w0.w = pack2(a1.z, a1.w);
            w1.x = pack2(a2.x, a2.y); w1.y = pack2(a2.z, a2.w);
            w1.z = pack2(a3.x, a3.y); w1.w = pack2(a3.z, a3.w);
            const int dbk = seg * 2 + db;
            *(uint4*)(vdst + dbk * 2048 + vbyte0)      = w0;
            *(uint4*)(vdst + dbk * 2048 + vbyte0 + 16) = w1;
        }
    } else {
        const uint4 z = {0u, 0u, 0u, 0u};
        #pragma unroll
        for (int i = 0; i < 4; ++i)
            *(uint4*)(kdst + srow * 256 + ((seg * 64 + i * 16) ^ swz)) = z;
        #pragma unroll
        for (int db = 0; db < 2; ++db){
            const int dbk = seg * 2 + db;
            *(uint4*)(vdst + dbk * 2048 + vbyte0)      = z;
            *(uint4*)(vdst + dbk * 2048 + vbyte0 + 16) = z;
        }
    }
}

// ============================ attention kernel (r12 loop, direct output, no split) ============================
// LDS 64KB: K dbuf [2][16KB] at 0, V dbuf [2][16KB] at 32768. 2 blocks/CU.
// Per-chunk: lgkm(0) -> s_barrier -> STAGE(ch+1) -> vmcnt(8) -> QK -> ISSUE 32 tr_reads ->
//            softmax (VALU-only steady state) -> lgkm(0) -> 32 PV MFMAs back-to-back.
__global__ __launch_bounds__(256, 2) void attn_kernel(
    const float* __restrict__ q,
    const int*   __restrict__ ctxlens,
    float*       __restrict__ out,
    const unsigned char* __restrict__ kimg,
    const unsigned char* __restrict__ vimg)
{
    __shared__ __align__(16) unsigned char lds[65536];

    const int tid  = threadIdx.x;
    const int w    = tid >> 6;
    const int lane = tid & 63;
    const int hh   = lane >> 4;
    const int cq   = lane & 15;

    const unsigned ldsb3 = (unsigned)(unsigned long long)(lds_as3_t*)(&lds[0]);

    const int item0 = blockIdx.x;                 // 0..511, long items first

    const int b   = item0 & 7;
    const int kvh = (item0 >> 3) & 7;
    const int s32 = 7 - (item0 >> 6);             // s32=7 (longest) dispatched first

    const int s0 = s32 * 32;
    const int ctxlen = ctxlens[b];
    const int vlim = ctxlen + (s32 + 1) * 32;
    const int nch  = (vlim + 63) >> 6;
    const int hq = kvh * GQA + w;

    const unsigned char* kstream = kimg + (size_t)(b * 8 + kvh) * KSTREAM;
    const unsigned char* vstream = vimg + (size_t)(b * 8 + kvh) * KSTREAM;

    #define STAGE(CH, PB) do { \
        const unsigned char* kg_ = kstream + (size_t)(CH) * CHUNK_B + (w * 4096 + lane * 16); \
        const unsigned char* vg_ = vstream + (size_t)(CH) * CHUNK_B + (w * 4096 + lane * 16); \
        _Pragma("unroll") \
        for (int i_ = 0; i_ < 4; ++i_){ \
            GLD16(kg_ + i_ * 1024, lds + (PB) * CHUNK_B + w * 4096 + i_ * 1024); \
            GLD16(vg_ + i_ * 1024, lds + 32768 + (PB) * CHUNK_B + w * 4096 + i_ * 1024); \
        } \
    } while (0)

    STAGE(0, 0);   // 8 GLD16 per wave — oldest vmem ops

    // Q fragments (B-operand), two 16-row tiles, pre-scaled into log2 domain
    B8 qf[2][4];
    #pragma unroll
    for (int u = 0; u < 2; ++u){
        const float* qrow = q + (size_t)(b * Q_LEN + s0 + u * 16 + cq) * (NUM_HEADS * HEAD_DIM)
                              + hq * HEAD_DIM;
        #pragma unroll
        for (int c = 0; c < 4; ++c){
            const float4 f0 = *(const float4*)(qrow + c * 32 + 8 * hh);
            const float4 f1 = *(const float4*)(qrow + c * 32 + 8 * hh + 4);
            const float sc = SCALE * LOG2E;
            qf[u][c].u.x = pack2(f0.x * sc, f0.y * sc);
            qf[u][c].u.y = pack2(f0.z * sc, f0.w * sc);
            qf[u][c].u.z = pack2(f1.x * sc, f1.y * sc);
            qf[u][c].u.w = pack2(f1.z * sc, f1.w * sc);
        }
    }

    f32x4 acc[2][8] = {};
    float mrun[2] = {-1e30f, -1e30f};
    float lp[2]   = {0.f, 0.f};

    for (int ch = 0; ch < nch; ++ch){
        const int pb = ch & 1;

        // ---- pipeline head: WAR barrier, prefetch issue, counted RAW wait ----
        asm volatile("s_waitcnt lgkmcnt(0)" ::: "memory");
        __builtin_amdgcn_s_barrier();
        __builtin_amdgcn_sched_barrier(0);
        if (ch + 1 < nch) {
            STAGE(ch + 1, pb ^ 1);
            __builtin_amdgcn_sched_barrier(0);
            asm volatile("s_waitcnt vmcnt(8)" ::: "memory");
        } else {
            asm volatile("s_waitcnt vmcnt(0)" ::: "memory");
        }
        __builtin_amdgcn_sched_barrier(0);

        const int base = ch * 64;
        const unsigned kb = (unsigned)(pb * CHUNK_B);

        // ---------------- QK^T (swapped): st[u][tf] = S^T[t][q] ----------------
        __builtin_amdgcn_s_setprio(1);
        f32x4 st[2][4] = {};
        #pragma unroll
        for (int c = 0; c < 4; ++c){
            #pragma unroll
            for (int tf = 0; tf < 4; ++tf){
                const int trow = tf * 16 + cq;
                const unsigned byte = kb + trow * 256 + ((c * 64 + hh * 16) ^ ((trow & 7) << 4));
                B8 kf; kf.u = *(const uint4*)(lds + byte);
                st[0][tf] = __builtin_amdgcn_mfma_f32_16x16x32_bf16(kf.v, qf[0][c].v, st[0][tf], 0, 0, 0);
                st[1][tf] = __builtin_amdgcn_mfma_f32_16x16x32_bf16(kf.v, qf[1][c].v, st[1][tf], 0, 0, 0);
            }
        }
        __builtin_amdgcn_s_setprio(0);

        // ---------------- EARLY ISSUE: all 32 V tr_reads (latency drains under softmax) ----------------
        const unsigned trb = ldsb3 + 32768u + (unsigned)(pb * CHUNK_B) + (unsigned)(hh * 128 + cq * 8);
        unsigned long long v00,v01,v02,v03,v04,v05,v06,v07,v08,v09,v10,v11,v12,v13,v14,v15;
        unsigned long long v16,v17,v18,v19,v20,v21,v22,v23,v24,v25,v26,v27,v28,v29,v30,v31;
        __builtin_amdgcn_sched_barrier(0);
        // kk=0, dc=0..7 (offsets dc*2048 + half*512)
        TRR(v00, trb, "0");     TRR(v01, trb, "512");
        TRR(v02, trb, "2048");  TRR(v03, trb, "2560");
        TRR(v04, trb, "4096");  TRR(v05, trb, "4608");
        TRR(v06, trb, "6144");  TRR(v07, trb, "6656");
        TRR(v08, trb, "8192");  TRR(v09, trb, "8704");
        TRR(v10, trb, "10240"); TRR(v11, trb, "10752");
        TRR(v12, trb, "12288"); TRR(v13, trb, "12800");
        TRR(v14, trb, "14336"); TRR(v15, trb, "14848");
        // kk=1, dc=0..7 (offsets dc*2048 + 1024 + half*512)
        TRR(v16, trb, "1024");  TRR(v17, trb, "1536");
        TRR(v18, trb, "3072");  TRR(v19, trb, "3584");
        TRR(v20, trb, "5120");  TRR(v21, trb, "5632");
        TRR(v22, trb, "7168");  TRR(v23, trb, "7680");
        TRR(v24, trb, "9216");  TRR(v25, trb, "9728");
        TRR(v26, trb, "11264"); TRR(v27, trb, "11776");
        TRR(v28, trb, "13312"); TRR(v29, trb, "13824");
        TRR(v30, trb, "15360"); TRR(v31, trb, "15872");
        __builtin_amdgcn_sched_barrier(0);

        // ---------------- softmax (shuffle-free defer-max; lgkm-free steady state) ----------------
        B8 af[2][2];
        const bool interior = (base + 64 <= vlim);
        #pragma unroll
        for (int u = 0; u < 2; ++u){
            float p[4][4];
            float pml = -1e30f;        // per-lane partial max over this lane's 16 t's
            if (interior){
                #pragma unroll
                for (int tf = 0; tf < 4; ++tf){
                    #pragma unroll
                    for (int r = 0; r < 4; ++r){
                        const float s = st[u][tf][r];
                        p[tf][r] = s;
                        pml = fmaxf(pml, s);
                    }
                }
            } else {
                #pragma unroll
                for (int tf = 0; tf < 4; ++tf){
                    #pragma unroll
                    for (int r = 0; r < 4; ++r){
                        const int t = base + tf * 16 + hh * 4 + r;
                        const float s = (t < vlim) ? st[u][tf][r] : -1e30f;
                        p[tf][r] = s;
                        pml = fmaxf(pml, s);
                    }
                }
            }
            // wave-max <= thr  <=>  all per-lane partial maxes <= thr (no cross-lane reduce needed)
            if (!__all(pml <= mrun[u] + RESCALE_THR)){
                float pm = fmaxf(pml, __shfl_xor(pml, 16));
                pm = fmaxf(pm, __shfl_xor(pm, 32));
                const float mnew  = fmaxf(mrun[u], pm);
                const float alpha = __builtin_amdgcn_exp2f(mrun[u] - mnew);
                mrun[u] = mnew;
                lp[u] *= alpha;
                float a4[4];
                #pragma unroll
                for (int r = 0; r < 4; ++r) a4[r] = __shfl(alpha, hh * 20 + r);
                #pragma unroll
                for (int dc = 0; dc < 8; ++dc){
                    #pragma unroll
                    for (int r = 0; r < 4; ++r) acc[u][dc][r] *= a4[r];
                }
            }
            const float m = mrun[u];
            float rsum = 0.f;
            #pragma unroll
            for (int tf = 0; tf < 4; ++tf){
                #pragma unroll
                for (int r = 0; r < 4; ++r){
                    const float e = __builtin_amdgcn_exp2f(p[tf][r] - m);
                    p[tf][r] = e;
                    rsum += e;
                }
            }
            lp[u] += rsum;

            // k-axis mapping: t(kk, 8hh+j) = 32kk + 16*(j>>2) + 4hh + (j&3)
            unsigned pk01[4], pk23[4];
            #pragma unroll
            for (int tf = 0; tf < 4; ++tf){
                pk01[tf] = pack2(p[tf][0], p[tf][1]);
                pk23[tf] = pack2(p[tf][2], p[tf][3]);
            }
            af[u][0].u.x = pk01[0]; af[u][0].u.y = pk23[0]; af[u][0].u.z = pk01[1]; af[u][0].u.w = pk23[1];
            af[u][1].u.x = pk01[2]; af[u][1].u.y = pk23[2]; af[u][1].u.z = pk01[3]; af[u][1].u.w = pk23[3];
        }

        // ---------------- PV: single wait, 32 MFMAs back-to-back ----------------
        {
            asm volatile("s_waitcnt lgkmcnt(0)" ::: "memory");
            __builtin_amdgcn_sched_barrier(0);
            __builtin_amdgcn_s_setprio(1);
            B8 vf;
            #define PVM(VA, VB, KK, DC) \
                vf.u.x=(unsigned)(VA); vf.u.y=(unsigned)((VA)>>32); \
                vf.u.z=(unsigned)(VB); vf.u.w=(unsigned)((VB)>>32); \
                acc[0][DC] = __builtin_amdgcn_mfma_f32_16x16x32_bf16(af[0][KK].v, vf.v, acc[0][DC], 0, 0, 0); \
                acc[1][DC] = __builtin_amdgcn_mfma_f32_16x16x32_bf16(af[1][KK].v, vf.v, acc[1][DC], 0, 0, 0);
            PVM(v00, v01, 0, 0)  PVM(v02, v03, 0, 1)  PVM(v04, v05, 0, 2)  PVM(v06, v07, 0, 3)
            PVM(v08, v09, 0, 4)  PVM(v10, v11, 0, 5)  PVM(v12, v13, 0, 6)  PVM(v14, v15, 0, 7)
            PVM(v16, v17, 1, 0)  PVM(v18, v19, 1, 1)  PVM(v20, v21, 1, 2)  PVM(v22, v23, 1, 3)
            PVM(v24, v25, 1, 4)  PVM(v26, v27, 1, 5)  PVM(v28, v29, 1, 6)  PVM(v30, v31, 1, 7)
            #undef PVM
            __builtin_amdgcn_s_setprio(0);
        }
        // no end-of-chunk barrier: next iteration's top barrier provides WAR separation
    }

    // ---------------- epilogue: normalize + direct write ----------------
    #pragma unroll
    for (int u = 0; u < 2; ++u){
        float l = lp[u];
        l += __shfl_xor(l, 16);
        l += __shfl_xor(l, 32);
        const float li = 1.0f / l;
        float li4[4];
        #pragma unroll
        for (int r = 0; r < 4; ++r) li4[r] = __shfl(li, hh * 20 + r);
        #pragma unroll
        for (int dc = 0; dc < 8; ++dc){
            #pragma unroll
            for (int r = 0; r < 4; ++r){
                const int so = s0 + u * 16 + hh * 4 + r;
                out[(size_t)(b * Q_LEN + so) * (NUM_HEADS * HEAD_DIM) + hq * HEAD_DIM + dc * 16 + cq]
                    = acc[u][dc][r] * li4[r];
            }
        }
    }
    #undef STAGE
}

extern "C" void kernel_launch(void* const* d_in, const int* in_sizes, int n_in,
                              void* d_out, int out_size, void* d_ws, size_t ws_size,
                              hipStream_t stream) {
    const float* q  = (const float*)d_in[0];
    const float* k  = (const float*)d_in[1];
    const float* v  = (const float*)d_in[2];
    const float* kc = (const float*)d_in[3];
    const float* vc = (const float*)d_in[4];
    const int*   pt = (const int*)d_in[5];
    const int*   cl = (const int*)d_in[6];
    float* o = (float*)d_out;

    unsigned char* kimg = (unsigned char*)d_ws + 256;
    unsigned char* vimg = kimg + (size_t)64 * KSTREAM;

    prep_kernel<<<dim3(NCH_MAX, 8, 8), 256, 0, stream>>>(k, v, kc, vc, pt, cl, kimg, vimg);
    attn_kernel<<<NITEMS, 256, 0, stream>>>(q, cl, o, kimg, vimg);
}

// Round 16
// 113.102 us; speedup vs baseline: 2.4791x; 1.0011x over previous
//
#include <hip/hip_runtime.h>
#include <hip/hip_bf16.h>

#define NUM_HEADS   32
#define NUM_KV_HEADS 8
#define HEAD_DIM    128
#define GQA          4
#define Q_LEN      256
#define MAX_PAGES  128
#define PAGE_SIZE   16
#define SCALE 0.08838834764831845f
#define LOG2E 1.44269504088896340736f
#define RESCALE_THR 8.0f

// 64-token chunks (best measured per-chunk economics)
#define NCH_MAX   36
#define CHUNK_B   16384
#define KSTREAM   ((size_t)NCH_MAX * CHUNK_B)
#define NITEMS    512

typedef __bf16 bf16x8 __attribute__((ext_vector_type(8)));
typedef float  f32x4  __attribute__((ext_vector_type(4)));

union B8 { uint4 u; bf16x8 v; };

__device__ __forceinline__ unsigned f2bf(float x){
    unsigned u = __builtin_bit_cast(unsigned, x);
    return (u + 0x7fffu + ((u >> 16) & 1u)) >> 16;
}
__device__ __forceinline__ unsigned pack2(float lo, float hi){
    return f2bf(lo) | (f2bf(hi) << 16);
}

typedef __attribute__((address_space(3))) unsigned char lds_as3_t;
typedef const __attribute__((address_space(1))) void gas_v;
typedef __attribute__((address_space(3))) void las_v;

#define GLD16(g, l) __builtin_amdgcn_global_load_lds((gas_v*)(g), (las_v*)(l), 16, 0, 0)

#define TRR(dst, base, OFF) asm volatile("ds_read_b64_tr_b16 %0, %1 offset:" OFF \
                                         : "=v"(dst) : "v"(base))

// ============================ pre-pass: gather + bf16 + pre-swizzle (64-t chunks) ============================
__global__ __launch_bounds__(256) void prep_kernel(
    const float* __restrict__ knew,
    const float* __restrict__ vnew,
    const float* __restrict__ kcache,
    const float* __restrict__ vcache,
    const int*   __restrict__ ptab,
    const int*   __restrict__ ctxlens,
    unsigned char* __restrict__ kimg,
    unsigned char* __restrict__ vimg)
{
    const int ch  = blockIdx.x;
    const int kvh = blockIdx.y;
    const int b   = blockIdx.z;
    const int ctxlen = ctxlens[b];
    const int lim = ctxlen + Q_LEN;
    const int base = ch * 64;
    if (base >= lim) return;

    const int tid  = threadIdx.x;
    const int srow = tid >> 2;
    const int seg  = tid & 3;
    const int t    = base + srow;

    unsigned char* kdst = kimg + (size_t)(b * 8 + kvh) * KSTREAM + (size_t)ch * CHUNK_B;
    unsigned char* vdst = vimg + (size_t)(b * 8 + kvh) * KSTREAM + (size_t)ch * CHUNK_B;
    const int swz    = (srow & 7) << 4;
    const int vbyte0 = (srow >> 2) * 128 + (srow & 3) * 32;

    if (t < lim){
        size_t roff;
        const float *ksrc, *vsrc;
        if (t < ctxlen){
            const int page = ptab[b * MAX_PAGES + (t >> 4)];
            roff = ((size_t)(page * PAGE_SIZE + (t & 15)) * NUM_KV_HEADS + kvh) * HEAD_DIM;
            ksrc = kcache + roff; vsrc = vcache + roff;
        } else {
            roff = ((size_t)(b * Q_LEN + (t - ctxlen)) * NUM_KV_HEADS + kvh) * HEAD_DIM;
            ksrc = knew + roff; vsrc = vnew + roff;
        }
        const float* kr = ksrc + seg * 32;
        const float* vr = vsrc + seg * 32;
        #pragma unroll
        for (int i = 0; i < 4; ++i){
            float4 a  = *(const float4*)(kr + i * 8);
            float4 c4 = *(const float4*)(kr + i * 8 + 4);
            uint4 wv;
            wv.x = pack2(a.x, a.y);  wv.y = pack2(a.z, a.w);
            wv.z = pack2(c4.x, c4.y); wv.w = pack2(c4.z, c4.w);
            *(uint4*)(kdst + srow * 256 + ((seg * 64 + i * 16) ^ swz)) = wv;
        }
        #pragma unroll
        for (int db = 0; db < 2; ++db){
            const float4 a0 = *(const float4*)(vr + db * 16 + 0);
            const float4 a1 = *(const float4*)(vr + db * 16 + 4);
            const float4 a2 = *(const float4*)(vr + db * 16 + 8);
            const float4 a3 = *(const float4*)(vr + db * 16 + 12);
            uint4 w0, w1;
            w0.x = pack2(a0.x, a0.y); w0.y = pack2(a0.z, a0.w);
            w0.z = pack2(a1.x, a1.y); w0.w = pack2(a1.z, a1.w);
            w1.x = pack2(a2.x, a2.y); w1.y = pack2(a2.z, a2.w);
            w1.z = pack2(a3.x, a3.y); w1.w = pack2(a3.z, a3.w);
            const int dbk = seg * 2 + db;
            *(uint4*)(vdst + dbk * 2048 + vbyte0)      = w0;
            *(uint4*)(vdst + dbk * 2048 + vbyte0 + 16) = w1;
        }
    } else {
        const uint4 z = {0u, 0u, 0u, 0u};
        #pragma unroll
        for (int i = 0; i < 4; ++i)
            *(uint4*)(kdst + srow * 256 + ((seg * 64 + i * 16) ^ swz)) = z;
        #pragma unroll
        for (int db = 0; db < 2; ++db){
            const int dbk = seg * 2 + db;
            *(uint4*)(vdst + dbk * 2048 + vbyte0)      = z;
            *(uint4*)(vdst + dbk * 2048 + vbyte0 + 16) = z;
        }
    }
}

// ============================ attention kernel (split-phase PV interleave) ============================
// LDS 64KB: K dbuf [2][16KB] at 0, V dbuf [2][16KB] at 32768. 2 blocks/CU.
// Per-chunk: lgkm(0) -> s_barrier -> STAGE(ch+1) -> vmcnt(8) -> QK -> issue 32 tr_reads ->
//            softmax(u0) -> lgkm(0) + unpack -> PV-u0 MFMAs || softmax(u1) VALU -> PV-u1 MFMAs.
__global__ __launch_bounds__(256, 2) void attn_kernel(
    const float* __restrict__ q,
    const int*   __restrict__ ctxlens,
    float*       __restrict__ out,
    const unsigned char* __restrict__ kimg,
    const unsigned char* __restrict__ vimg)
{
    __shared__ __align__(16) unsigned char lds[65536];

    const int tid  = threadIdx.x;
    const int w    = tid >> 6;
    const int lane = tid & 63;
    const int hh   = lane >> 4;
    const int cq   = lane & 15;

    const unsigned ldsb3 = (unsigned)(unsigned long long)(lds_as3_t*)(&lds[0]);

    const int item0 = blockIdx.x;                 // 0..511, long items first

    const int b   = item0 & 7;
    const int kvh = (item0 >> 3) & 7;
    const int s32 = 7 - (item0 >> 6);             // s32=7 (longest) dispatched first

    const int s0 = s32 * 32;
    const int ctxlen = ctxlens[b];
    const int vlim = ctxlen + (s32 + 1) * 32;
    const int nch  = (vlim + 63) >> 6;
    const int hq = kvh * GQA + w;

    const unsigned char* kstream = kimg + (size_t)(b * 8 + kvh) * KSTREAM;
    const unsigned char* vstream = vimg + (size_t)(b * 8 + kvh) * KSTREAM;

    #define STAGE(CH, PB) do { \
        const unsigned char* kg_ = kstream + (size_t)(CH) * CHUNK_B + (w * 4096 + lane * 16); \
        const unsigned char* vg_ = vstream + (size_t)(CH) * CHUNK_B + (w * 4096 + lane * 16); \
        _Pragma("unroll") \
        for (int i_ = 0; i_ < 4; ++i_){ \
            GLD16(kg_ + i_ * 1024, lds + (PB) * CHUNK_B + w * 4096 + i_ * 1024); \
            GLD16(vg_ + i_ * 1024, lds + 32768 + (PB) * CHUNK_B + w * 4096 + i_ * 1024); \
        } \
    } while (0)

    STAGE(0, 0);   // 8 GLD16 per wave — oldest vmem ops

    // Q fragments (B-operand), two 16-row tiles, pre-scaled into log2 domain
    B8 qf[2][4];
    #pragma unroll
    for (int u = 0; u < 2; ++u){
        const float* qrow = q + (size_t)(b * Q_LEN + s0 + u * 16 + cq) * (NUM_HEADS * HEAD_DIM)
                              + hq * HEAD_DIM;
        #pragma unroll
        for (int c = 0; c < 4; ++c){
            const float4 f0 = *(const float4*)(qrow + c * 32 + 8 * hh);
            const float4 f1 = *(const float4*)(qrow + c * 32 + 8 * hh + 4);
            const float sc = SCALE * LOG2E;
            qf[u][c].u.x = pack2(f0.x * sc, f0.y * sc);
            qf[u][c].u.y = pack2(f0.z * sc, f0.w * sc);
            qf[u][c].u.z = pack2(f1.x * sc, f1.y * sc);
            qf[u][c].u.w = pack2(f1.z * sc, f1.w * sc);
        }
    }

    f32x4 acc[2][8] = {};
    float mrun[2] = {-1e30f, -1e30f};
    float lp[2]   = {0.f, 0.f};

    // per-u softmax: produces af[U], updates mrun/lp/acc[U] (rescale)
    #define SOFTMAX_U(U) do { \
        float p_[4][4]; \
        float pml_ = -1e30f; \
        if (interior){ \
            _Pragma("unroll") \
            for (int tf = 0; tf < 4; ++tf){ \
                _Pragma("unroll") \
                for (int r = 0; r < 4; ++r){ \
                    const float s_ = st[U][tf][r]; \
                    p_[tf][r] = s_; \
                    pml_ = fmaxf(pml_, s_); \
                } \
            } \
        } else { \
            _Pragma("unroll") \
            for (int tf = 0; tf < 4; ++tf){ \
                _Pragma("unroll") \
                for (int r = 0; r < 4; ++r){ \
                    const int t_ = base + tf * 16 + hh * 4 + r; \
                    const float s_ = (t_ < vlim) ? st[U][tf][r] : -1e30f; \
                    p_[tf][r] = s_; \
                    pml_ = fmaxf(pml_, s_); \
                } \
            } \
        } \
        if (!__all(pml_ <= mrun[U] + RESCALE_THR)){ \
            float pm_ = fmaxf(pml_, __shfl_xor(pml_, 16)); \
            pm_ = fmaxf(pm_, __shfl_xor(pm_, 32)); \
            const float mnew_  = fmaxf(mrun[U], pm_); \
            const float alpha_ = __builtin_amdgcn_exp2f(mrun[U] - mnew_); \
            mrun[U] = mnew_; \
            lp[U] *= alpha_; \
            float a4_[4]; \
            _Pragma("unroll") \
            for (int r = 0; r < 4; ++r) a4_[r] = __shfl(alpha_, hh * 20 + r); \
            _Pragma("unroll") \
            for (int dc = 0; dc < 8; ++dc){ \
                _Pragma("unroll") \
                for (int r = 0; r < 4; ++r) acc[U][dc][r] *= a4_[r]; \
            } \
        } \
        const float m_ = mrun[U]; \
        float rsum_ = 0.f; \
        _Pragma("unroll") \
        for (int tf = 0; tf < 4; ++tf){ \
            _Pragma("unroll") \
            for (int r = 0; r < 4; ++r){ \
                const float e_ = __builtin_amdgcn_exp2f(p_[tf][r] - m_); \
                p_[tf][r] = e_; \
                rsum_ += e_; \
            } \
        } \
        lp[U] += rsum_; \
        unsigned pk01_[4], pk23_[4]; \
        _Pragma("unroll") \
        for (int tf = 0; tf < 4; ++tf){ \
            pk01_[tf] = pack2(p_[tf][0], p_[tf][1]); \
            pk23_[tf] = pack2(p_[tf][2], p_[tf][3]); \
        } \
        af[U][0].u.x = pk01_[0]; af[U][0].u.y = pk23_[0]; af[U][0].u.z = pk01_[1]; af[U][0].u.w = pk23_[1]; \
        af[U][1].u.x = pk01_[2]; af[U][1].u.y = pk23_[2]; af[U][1].u.z = pk01_[3]; af[U][1].u.w = pk23_[3]; \
    } while (0)

    for (int ch = 0; ch < nch; ++ch){
        const int pb = ch & 1;

        // ---- pipeline head: WAR barrier, prefetch issue, counted RAW wait ----
        asm volatile("s_waitcnt lgkmcnt(0)" ::: "memory");
        __builtin_amdgcn_s_barrier();
        __builtin_amdgcn_sched_barrier(0);
        if (ch + 1 < nch) {
            STAGE(ch + 1, pb ^ 1);
            __builtin_amdgcn_sched_barrier(0);
            asm volatile("s_waitcnt vmcnt(8)" ::: "memory");
        } else {
            asm volatile("s_waitcnt vmcnt(0)" ::: "memory");
        }
        __builtin_amdgcn_sched_barrier(0);

        const int base = ch * 64;
        const unsigned kb = (unsigned)(pb * CHUNK_B);

        // ---------------- QK^T (swapped): st[u][tf] = S^T[t][q] ----------------
        __builtin_amdgcn_s_setprio(1);
        f32x4 st[2][4] = {};
        #pragma unroll
        for (int c = 0; c < 4; ++c){
            #pragma unroll
            for (int tf = 0; tf < 4; ++tf){
                const int trow = tf * 16 + cq;
                const unsigned byte = kb + trow * 256 + ((c * 64 + hh * 16) ^ ((trow & 7) << 4));
                B8 kf; kf.u = *(const uint4*)(lds + byte);
                st[0][tf] = __builtin_amdgcn_mfma_f32_16x16x32_bf16(kf.v, qf[0][c].v, st[0][tf], 0, 0, 0);
                st[1][tf] = __builtin_amdgcn_mfma_f32_16x16x32_bf16(kf.v, qf[1][c].v, st[1][tf], 0, 0, 0);
            }
        }
        __builtin_amdgcn_s_setprio(0);

        // ---------------- EARLY ISSUE: all 32 V tr_reads (latency drains under softmax u0) ----------------
        const unsigned trb = ldsb3 + 32768u + (unsigned)(pb * CHUNK_B) + (unsigned)(hh * 128 + cq * 8);
        unsigned long long v00,v01,v02,v03,v04,v05,v06,v07,v08,v09,v10,v11,v12,v13,v14,v15;
        unsigned long long v16,v17,v18,v19,v20,v21,v22,v23,v24,v25,v26,v27,v28,v29,v30,v31;
        __builtin_amdgcn_sched_barrier(0);
        // kk=0, dc=0..7 (offsets dc*2048 + half*512)
        TRR(v00, trb, "0");     TRR(v01, trb, "512");
        TRR(v02, trb, "2048");  TRR(v03, trb, "2560");
        TRR(v04, trb, "4096");  TRR(v05, trb, "4608");
        TRR(v06, trb, "6144");  TRR(v07, trb, "6656");
        TRR(v08, trb, "8192");  TRR(v09, trb, "8704");
        TRR(v10, trb, "10240"); TRR(v11, trb, "10752");
        TRR(v12, trb, "12288"); TRR(v13, trb, "12800");
        TRR(v14, trb, "14336"); TRR(v15, trb, "14848");
        // kk=1, dc=0..7 (offsets dc*2048 + 1024 + half*512)
        TRR(v16, trb, "1024");  TRR(v17, trb, "1536");
        TRR(v18, trb, "3072");  TRR(v19, trb, "3584");
        TRR(v20, trb, "5120");  TRR(v21, trb, "5632");
        TRR(v22, trb, "7168");  TRR(v23, trb, "7680");
        TRR(v24, trb, "9216");  TRR(v25, trb, "9728");
        TRR(v26, trb, "11264"); TRR(v27, trb, "11776");
        TRR(v28, trb, "13312"); TRR(v29, trb, "13824");
        TRR(v30, trb, "15360"); TRR(v31, trb, "15872");
        __builtin_amdgcn_sched_barrier(0);

        B8 af[2][2];
        const bool interior = (base + 64 <= vlim);

        // ---------------- phase 1: softmax u=0 (tr latency drains underneath) ----------------
        SOFTMAX_U(0);

        // ---------------- phase 2: wait trs, unpack into persistent fragments ----------------
        asm volatile("s_waitcnt lgkmcnt(0)" ::: "memory");
        __builtin_amdgcn_sched_barrier(0);
        B8 vfs[16];
        #define UNP(I, VA, VB) \
            vfs[I].u.x=(unsigned)(VA); vfs[I].u.y=(unsigned)((VA)>>32); \
            vfs[I].u.z=(unsigned)(VB); vfs[I].u.w=(unsigned)((VB)>>32);
        UNP(0,  v00, v01)  UNP(1,  v02, v03)  UNP(2,  v04, v05)  UNP(3,  v06, v07)
        UNP(4,  v08, v09)  UNP(5,  v10, v11)  UNP(6,  v12, v13)  UNP(7,  v14, v15)
        UNP(8,  v16, v17)  UNP(9,  v18, v19)  UNP(10, v20, v21)  UNP(11, v22, v23)
        UNP(12, v24, v25)  UNP(13, v26, v27)  UNP(14, v28, v29)  UNP(15, v30, v31)
        #undef UNP

        // ---------------- phase 3: PV-u0 MFMAs issue; softmax u=1 VALU overlaps completion ----------------
        __builtin_amdgcn_s_setprio(1);
        #pragma unroll
        for (int i = 0; i < 8; ++i)
            acc[0][i] = __builtin_amdgcn_mfma_f32_16x16x32_bf16(af[0][0].v, vfs[i].v, acc[0][i], 0, 0, 0);
        #pragma unroll
        for (int i = 0; i < 8; ++i)
            acc[0][i] = __builtin_amdgcn_mfma_f32_16x16x32_bf16(af[0][1].v, vfs[8 + i].v, acc[0][i], 0, 0, 0);
        __builtin_amdgcn_s_setprio(0);

        SOFTMAX_U(1);

        // ---------------- phase 4: PV-u1 MFMAs ----------------
        __builtin_amdgcn_s_setprio(1);
        #pragma unroll
        for (int i = 0; i < 8; ++i)
            acc[1][i] = __builtin_amdgcn_mfma_f32_16x16x32_bf16(af[1][0].v, vfs[i].v, acc[1][i], 0, 0, 0);
        #pragma unroll
        for (int i = 0; i < 8; ++i)
            acc[1][i] = __builtin_amdgcn_mfma_f32_16x16x32_bf16(af[1][1].v, vfs[8 + i].v, acc[1][i], 0, 0, 0);
        __builtin_amdgcn_s_setprio(0);
        // no end-of-chunk barrier: next iteration's top barrier provides WAR separation
    }

    // ---------------- epilogue: normalize + direct write ----------------
    #pragma unroll
    for (int u = 0; u < 2; ++u){
        float l = lp[u];
        l += __shfl_xor(l, 16);
        l += __shfl_xor(l, 32);
        const float li = 1.0f / l;
        float li4[4];
        #pragma unroll
        for (int r = 0; r < 4; ++r) li4[r] = __shfl(li, hh * 20 + r);
        #pragma unroll
        for (int dc = 0; dc < 8; ++dc){
            #pragma unroll
            for (int r = 0; r < 4; ++r){
                const int so = s0 + u * 16 + hh * 4 + r;
                out[(size_t)(b * Q_LEN + so) * (NUM_HEADS * HEAD_DIM) + hq * HEAD_DIM + dc * 16 + cq]
                    = acc[u][dc][r] * li4[r];
            }
        }
    }
    #undef STAGE
    #undef SOFTMAX_U
}

extern "C" void kernel_launch(void* const* d_in, const int* in_sizes, int n_in,
                              void* d_out, int out_size, void* d_ws, size_t ws_size,
                              hipStream_t stream) {
    const float* q  = (const float*)d_in[0];
    const float* k  = (const float*)d_in[1];
    const float* v  = (const float*)d_in[2];
    const float* kc = (const float*)d_in[3];
    const float* vc = (const float*)d_in[4];
    const int*   pt = (const int*)d_in[5];
    const int*   cl = (const int*)d_in[6];
    float* o = (float*)d_out;

    unsigned char* kimg = (unsigned char*)d_ws + 256;
    unsigned char* vimg = kimg + (size_t)64 * KSTREAM;

    prep_kernel<<<dim3(NCH_MAX, 8, 8), 256, 0, stream>>>(k, v, kc, vc, pt, cl, kimg, vimg);
    attn_kernel<<<NITEMS, 256, 0, stream>>>(q, cl, o, kimg, vimg);
}